// Round 5
// baseline (1075.981 us; speedup 1.0000x reference)
//
#include <hip/hip_runtime.h>
#include <hip/hip_bf16.h>

// GraphSAGE 3-layer, N=50000 nodes, E=400000 edges, dims 512->512->512->128.
// Round 4 -> 5: the 2-barrier-per-K-iteration GEMM was latency-bound at 10%
// MfmaUtil regardless of staging scheme (__syncthreads drains vmcnt -> <1KB/CU
// in flight vs ~9KB needed). New GEMM: 64-col weight slice resident in LDS
// (64KB, loaded once per pass), K-loop has ZERO barriers -- A fragments are
// loaded global->register (16 rows x 64B contiguous per wave instr), software
// pipelined, MFMA'd against LDS B. 2 blocks/CU; 8 col-tiles of one row-strip
// grouped per XCD for L2 A-reuse.

#define N_NODES 50000
#define N_EDGES 400000

typedef unsigned short u16;
typedef unsigned int u32;
typedef __attribute__((ext_vector_type(8))) short short8;
typedef __attribute__((ext_vector_type(4))) float floatx4;

__device__ __forceinline__ u16 f32_to_bf16(float f) {
    u32 u = __float_as_uint(f);
    u32 r = 0x7FFFu + ((u >> 16) & 1u);
    return (u16)((u + r) >> 16);
}
__device__ __forceinline__ float bf16_to_f32(u32 lo16) {
    return __uint_as_float(lo16 << 16);
}

__global__ __launch_bounds__(256) void zero4_kernel(float4* __restrict__ p, int n4) {
    int i = blockIdx.x * 256 + threadIdx.x;
    if (i < n4) p[i] = make_float4(0.f, 0.f, 0.f, 0.f);
}

__global__ __launch_bounds__(256) void hist_kernel(const int* __restrict__ dst,
                                                   int* __restrict__ deg, int E) {
    int e = blockIdx.x * 256 + threadIdx.x;
    if (e < E) atomicAdd(&deg[dst[e]], 1);
}

__global__ __launch_bounds__(256) void scan_reduce(const int* __restrict__ v,
                                                   int* __restrict__ bsums, int n) {
    __shared__ int sh[256];
    int i = blockIdx.x * 256 + threadIdx.x;
    sh[threadIdx.x] = (i < n) ? v[i] : 0;
    __syncthreads();
    for (int off = 128; off > 0; off >>= 1) {
        if (threadIdx.x < off) sh[threadIdx.x] += sh[threadIdx.x + off];
        __syncthreads();
    }
    if (threadIdx.x == 0) bsums[blockIdx.x] = sh[0];
}

__global__ __launch_bounds__(256) void scan_sums(int* __restrict__ bsums, int nb) {
    __shared__ int sh[256];
    int t = threadIdx.x;
    int val = (t < nb) ? bsums[t] : 0;
    sh[t] = val;
    __syncthreads();
    for (int off = 1; off < 256; off <<= 1) {
        int v = (t >= off) ? sh[t - off] : 0;
        __syncthreads();
        sh[t] += v;
        __syncthreads();
    }
    if (t < nb) bsums[t] = sh[t] - val;
}

__global__ __launch_bounds__(256) void scan_final(int* __restrict__ v,
                                                  const int* __restrict__ bsums, int n) {
    __shared__ int sh[256];
    int t = threadIdx.x;
    int i = blockIdx.x * 256 + t;
    int val = (i < n) ? v[i] : 0;
    sh[t] = val;
    __syncthreads();
    for (int off = 1; off < 256; off <<= 1) {
        int x = (t >= off) ? sh[t - off] : 0;
        __syncthreads();
        sh[t] += x;
        __syncthreads();
    }
    int excl = sh[t] - val + bsums[blockIdx.x];
    if (i < n) v[i] = excl;
    if (i == n - 1) v[n] = excl + val;
}

__global__ __launch_bounds__(256) void fill_kernel(const int* __restrict__ src,
                                                   const int* __restrict__ dst,
                                                   const int* __restrict__ row_start,
                                                   int* __restrict__ cursor,
                                                   int* __restrict__ csr_src, int E) {
    int e = blockIdx.x * 256 + threadIdx.x;
    if (e < E) {
        int d = dst[e];
        int pos = row_start[d] + atomicAdd(&cursor[d], 1);
        csr_src[pos] = src[e];
    }
}

// f32 [n8*8] -> bf16, 8 elems/thread
__global__ __launch_bounds__(256) void convert_bf16(const float* __restrict__ in,
                                                    u16* __restrict__ out, int n8) {
    int i = blockIdx.x * 256 + threadIdx.x;
    if (i >= n8) return;
    const float4* p = (const float4*)in + (size_t)i * 2;
    float4 v0 = p[0], v1 = p[1];
    uint4 o;
    o.x = (u32)f32_to_bf16(v0.x) | ((u32)f32_to_bf16(v0.y) << 16);
    o.y = (u32)f32_to_bf16(v0.z) | ((u32)f32_to_bf16(v0.w) << 16);
    o.z = (u32)f32_to_bf16(v1.x) | ((u32)f32_to_bf16(v1.y) << 16);
    o.w = (u32)f32_to_bf16(v1.z) | ((u32)f32_to_bf16(v1.w) << 16);
    ((uint4*)out)[i] = o;
}

// W [K][N] f32 -> WT [N][K] bf16, 32x32 tiles
__global__ __launch_bounds__(256) void transpose_w(const float* __restrict__ W,
                                                   u16* __restrict__ WT,
                                                   int K, int N) {
    __shared__ float t[32][33];
    int n0 = blockIdx.x * 32, k0 = blockIdx.y * 32;
    int c = threadIdx.x & 31, r0 = threadIdx.x >> 5;
    for (int r = r0; r < 32; r += 8)
        t[r][c] = W[(size_t)(k0 + r) * N + n0 + c];
    __syncthreads();
    for (int r = r0; r < 32; r += 8)
        WT[(size_t)(n0 + r) * K + k0 + c] = f32_to_bf16(t[c][r]);
}

// One wave per node: mean of neighbor bf16 rows, fp32 accum, bf16 out.
__global__ __launch_bounds__(256) void gather_mean_bf16(const u16* __restrict__ X,
                                                        const int* __restrict__ row_start,
                                                        const int* __restrict__ csr_src,
                                                        u16* __restrict__ agg, int M) {
    int node = (blockIdx.x * 256 + threadIdx.x) >> 6;
    int lane = threadIdx.x & 63;
    if (node >= M) return;
    int beg = row_start[node], end = row_start[node + 1];
    float a[8] = {0.f, 0.f, 0.f, 0.f, 0.f, 0.f, 0.f, 0.f};
    for (int c = beg; c < end; c += 64) {
        int nb = min(64, end - c);
        int eid = (lane < nb) ? csr_src[c + lane] : 0;
        for (int i = 0; i < nb; ++i) {
            int s = __shfl(eid, i);
            uint4 v = ((const uint4*)(X + (size_t)s * 512))[lane];
            a[0] += bf16_to_f32(v.x & 0xffffu); a[1] += bf16_to_f32(v.x >> 16);
            a[2] += bf16_to_f32(v.y & 0xffffu); a[3] += bf16_to_f32(v.y >> 16);
            a[4] += bf16_to_f32(v.z & 0xffffu); a[5] += bf16_to_f32(v.z >> 16);
            a[6] += bf16_to_f32(v.w & 0xffffu); a[7] += bf16_to_f32(v.w >> 16);
        }
    }
    float inv = 1.0f / fmaxf((float)(end - beg), 1.0f);
    uint4 o;
    o.x = (u32)f32_to_bf16(a[0] * inv) | ((u32)f32_to_bf16(a[1] * inv) << 16);
    o.y = (u32)f32_to_bf16(a[2] * inv) | ((u32)f32_to_bf16(a[3] * inv) << 16);
    o.z = (u32)f32_to_bf16(a[4] * inv) | ((u32)f32_to_bf16(a[5] * inv) << 16);
    o.w = (u32)f32_to_bf16(a[6] * inv) | ((u32)f32_to_bf16(a[7] * inv) << 16);
    ((uint4*)(agg + (size_t)node * 512))[lane] = o;
}

// C[M,N] = A1@B1T' + A2@B2T' + bias (B*T stored [N][512]), optional relu.
// Block tile: 128 rows x 64 cols. 4 waves: 2 in m (64 rows) x 2 in n (32 cols).
// Per pass: stage B slice (64 cols x 512 K = 64KB) into LDS once, then a
// BARRIER-FREE K-loop: A frags global->reg (pipelined 1 chunk ahead), 8 MFMA
// per 32-k chunk per wave. LDS B layout: granule g = kc2*64 + col (16B each).
__global__ __launch_bounds__(256) void gemm_blds(
    const u16* __restrict__ A1, const u16* __restrict__ A2,
    const u16* __restrict__ B1T, const u16* __restrict__ B2T,
    const float* __restrict__ bias,
    u16* __restrict__ Cb, float* __restrict__ Cf,
    int M, int N, int relu, int nStrips, int nCols) {
    __shared__ u16 Bsh[32768];  // 64 KB

    // Swizzle: group = 8 strips x nCols col-tiles; same strip -> same b%8 -> same XCD
    const int grp = 8 * nCols;
    int b = blockIdx.x;
    int strip = (b / grp) * 8 + (b % 8);
    int colt = (b % grp) >> 3;
    if (strip >= nStrips) return;
    const int row0 = strip * 128, col0 = colt * 64;

    const int t = threadIdx.x;
    const int w = t >> 6, lane = t & 63;
    const int wm = (w & 1) * 64, wn = (w >> 1) * 32;
    const int l15 = lane & 15, kq = lane >> 4;

    floatx4 acc[4][2];
#pragma unroll
    for (int i = 0; i < 4; ++i) {
        acc[i][0] = floatx4{0.f, 0.f, 0.f, 0.f};
        acc[i][1] = floatx4{0.f, 0.f, 0.f, 0.f};
    }

    // A row bases (elements); +kc*32 + kq*8 per chunk. 64B contiguous per row.
    size_t aoff[4];
#pragma unroll
    for (int mt = 0; mt < 4; ++mt) {
        int r = min(row0 + wm + mt * 16 + l15, M - 1);
        aoff[mt] = (size_t)r * 512 + kq * 8;
    }

    // B staging assignment: thread -> col = t&63, 16 granules starting (t>>6)*16
    const int colS = t & 63;
    const int kb = (w) * 16;
    const size_t bgbase = (size_t)(col0 + colS) * 512;

    const short8* Bv = (const short8*)Bsh;

    for (int pass = 0; pass < 2; ++pass) {
        const u16* Ap = pass ? A2 : A1;
        const u16* Bp = pass ? B2T : B1T;

        __syncthreads();  // pass-1 reads done before restage (no-op cost on pass 0)
#pragma unroll
        for (int i = 0; i < 16; ++i) {
            ((uint4*)Bsh)[(kb + i) * 64 + colS] =
                *(const uint4*)(Bp + bgbase + (size_t)(kb + i) * 8);
        }
        __syncthreads();  // B slice visible

        uint4 na[4];
#pragma unroll
        for (int mt = 0; mt < 4; ++mt)
            na[mt] = *(const uint4*)(Ap + aoff[mt]);

        for (int kc = 0; kc < 16; ++kc) {
            uint4 ca[4];
#pragma unroll
            for (int mt = 0; mt < 4; ++mt) ca[mt] = na[mt];
            if (kc < 15) {
                int ko = (kc + 1) * 32;
#pragma unroll
                for (int mt = 0; mt < 4; ++mt)
                    na[mt] = *(const uint4*)(Ap + aoff[mt] + ko);
            }
            const int bg = (kc * 4 + kq) * 64 + wn;
            short8 b0 = Bv[bg + l15];
            short8 b1 = Bv[bg + 16 + l15];
#pragma unroll
            for (int mt = 0; mt < 4; ++mt) {
                short8 av = __builtin_bit_cast(short8, ca[mt]);
                acc[mt][0] = __builtin_amdgcn_mfma_f32_16x16x32_bf16(
                    av, b0, acc[mt][0], 0, 0, 0);
                acc[mt][1] = __builtin_amdgcn_mfma_f32_16x16x32_bf16(
                    av, b1, acc[mt][1], 0, 0, 0);
            }
        }
    }

    // Epilogue. C/D: col = lane&15, row = (lane>>4)*4 + reg  [m89/m91]
#pragma unroll
    for (int nt = 0; nt < 2; ++nt) {
        int col = col0 + wn + nt * 16 + l15;
        float bv = bias[col];
#pragma unroll
        for (int mt = 0; mt < 4; ++mt) {
#pragma unroll
            for (int r = 0; r < 4; ++r) {
                int row = row0 + wm + mt * 16 + kq * 4 + r;
                if (row >= M) continue;
                float v = acc[mt][nt][r] + bv;
                if (relu) v = fmaxf(v, 0.f);
                if (Cf) Cf[(size_t)row * N + col] = v;
                else Cb[(size_t)row * N + col] = f32_to_bf16(v);
            }
        }
    }
}

// In-place log_softmax over rows of 128; one wave per row.
__global__ __launch_bounds__(256) void logsoftmax128(float* __restrict__ out, int M) {
    int row = blockIdx.x * 4 + (threadIdx.x >> 6);
    int lane = threadIdx.x & 63;
    if (row >= M) return;
    float* p = out + (size_t)row * 128;
    float a = p[lane];
    float b = p[lane + 64];
    float m = fmaxf(a, b);
#pragma unroll
    for (int off = 32; off > 0; off >>= 1) m = fmaxf(m, __shfl_xor(m, off));
    float s = expf(a - m) + expf(b - m);
#pragma unroll
    for (int off = 32; off > 0; off >>= 1) s += __shfl_xor(s, off);
    float ls = m + logf(s);
    p[lane] = a - ls;
    p[lane + 64] = b - ls;
}

extern "C" void kernel_launch(void* const* d_in, const int* in_sizes, int n_in,
                              void* d_out, int out_size, void* d_ws, size_t ws_size,
                              hipStream_t stream) {
    const float* x    = (const float*)d_in[0];
    const int*   ei   = (const int*)d_in[1];
    const float* W1_l = (const float*)d_in[2];
    const float* b1   = (const float*)d_in[3];
    const float* W1_r = (const float*)d_in[4];
    const float* W2_l = (const float*)d_in[5];
    const float* b2   = (const float*)d_in[6];
    const float* W2_r = (const float*)d_in[7];
    const float* W3_l = (const float*)d_in[8];
    const float* b3   = (const float*)d_in[9];
    const float* W3_r = (const float*)d_in[10];
    float* out = (float*)d_out;

    const int* src = ei;
    const int* dst = ei + N_EDGES;

    // Workspace layout (bytes from base):
    char* base = (char*)d_ws;
    int* row_start = (int*)(base);                    // 50052 ints
    int* cursor    = (int*)(base + 200208);           // 50052 ints
    int* bsums     = (int*)(base + 400416);           // 512 ints
    int* csr_src   = (int*)(base + 402464);           // 400000 ints -> end 2002464
    u16* xb   = (u16*)(base + 2002464);               // 25.6M bf16
    u16* aggb = (u16*)(base + 53202464);
    u16* h1b  = (u16*)(base + 104402464);
    u16* h2b  = (u16*)(base + 155602464);
    u16* w1lT = (u16*)(base + 206802464);             // [512][512]
    u16* w1rT = (u16*)(base + 207326752);
    u16* w2lT = (u16*)(base + 207851040);
    u16* w2rT = (u16*)(base + 208375328);
    u16* w3lT = (u16*)(base + 208899616);             // [128][512]
    u16* w3rT = (u16*)(base + 209030688);             // end 209161760

    const int E = N_EDGES, M = N_NODES;
    const int nblk = (M + 255) / 256;

    // ---- CSR build ----
    zero4_kernel<<<(25154 + 255) / 256, 256, 0, stream>>>((float4*)d_ws, 25154);
    hist_kernel<<<(E + 255) / 256, 256, 0, stream>>>(dst, row_start, E);
    scan_reduce<<<nblk, 256, 0, stream>>>(row_start, bsums, M);
    scan_sums<<<1, 256, 0, stream>>>(bsums, nblk);
    scan_final<<<nblk, 256, 0, stream>>>(row_start, bsums, M);
    fill_kernel<<<(E + 255) / 256, 256, 0, stream>>>(src, dst, row_start, cursor,
                                                     csr_src, E);

    // ---- conversions ----
    convert_bf16<<<(3200000 + 255) / 256, 256, 0, stream>>>(x, xb, 3200000);
    transpose_w<<<dim3(16, 16), 256, 0, stream>>>(W1_l, w1lT, 512, 512);
    transpose_w<<<dim3(16, 16), 256, 0, stream>>>(W1_r, w1rT, 512, 512);
    transpose_w<<<dim3(16, 16), 256, 0, stream>>>(W2_l, w2lT, 512, 512);
    transpose_w<<<dim3(16, 16), 256, 0, stream>>>(W2_r, w2rT, 512, 512);
    transpose_w<<<dim3(4, 16), 256, 0, stream>>>(W3_l, w3lT, 512, 128);
    transpose_w<<<dim3(4, 16), 256, 0, stream>>>(W3_r, w3rT, 512, 128);

    const int gather_blocks = (M * 64 + 255) / 256;
    const int nStrips = (M + 127) / 128;                 // 391
    const int grid512 = ((nStrips + 7) / 8) * 8 * 8;     // 3136 (nCols=8)
    const int grid128 = ((nStrips + 7) / 8) * 8 * 2;     // 784  (nCols=2)

    // ---- layer 1 ----
    gather_mean_bf16<<<gather_blocks, 256, 0, stream>>>(xb, row_start, csr_src, aggb, M);
    gemm_blds<<<grid512, 256, 0, stream>>>(aggb, xb, w1lT, w1rT, b1,
                                           h1b, nullptr, M, 512, 1, nStrips, 8);
    // ---- layer 2 ----
    gather_mean_bf16<<<gather_blocks, 256, 0, stream>>>(h1b, row_start, csr_src, aggb, M);
    gemm_blds<<<grid512, 256, 0, stream>>>(aggb, h1b, w2lT, w2rT, b2,
                                           h2b, nullptr, M, 512, 1, nStrips, 8);
    // ---- layer 3 ----
    gather_mean_bf16<<<gather_blocks, 256, 0, stream>>>(h2b, row_start, csr_src, aggb, M);
    gemm_blds<<<grid128, 256, 0, stream>>>(aggb, h2b, w3lT, w3rT, b3,
                                           nullptr, out, M, 128, 0, nStrips, 2);

    logsoftmax128<<<(M + 3) / 4, 256, 0, stream>>>(out, M);
}

// Round 6
// 897.678 us; speedup vs baseline: 1.1986x; 1.1986x over previous
//
#include <hip/hip_runtime.h>
#include <hip/hip_bf16.h>

// GraphSAGE 3-layer, N=50000 nodes, E=400000 edges, dims 512->512->512->128.
// Round 5 -> 6: revert r5 (64KB-LDS barrier-free GEMM regressed, 284us).
// Back to r4's 128x128/BK=32 double-buffered GEMM with ONE structural fix:
// r4 issued the prefetch BEFORE the second __syncthreads, and HIP drains
// vmcnt(0) at every barrier -> prefetch never overlapped compute (why r3 and
// r4 both sat at 205us / 10% MfmaUtil). New loop has ONE barrier per
// iteration and issues the prefetch AFTER it:
//   store regs->LDS[buf]; barrier; load(it+1); mfma(LDS[buf])
// Double buffering makes one barrier sufficient (a wave can only overwrite
// buf after all waves passed the barrier, which is after their compute of
// the previous buf-parity iteration).

#define N_NODES 50000
#define N_EDGES 400000

typedef unsigned short u16;
typedef unsigned int u32;
typedef __attribute__((ext_vector_type(8))) short short8;
typedef __attribute__((ext_vector_type(4))) float floatx4;

__device__ __forceinline__ u16 f32_to_bf16(float f) {
    u32 u = __float_as_uint(f);
    u32 r = 0x7FFFu + ((u >> 16) & 1u);
    return (u16)((u + r) >> 16);
}
__device__ __forceinline__ float bf16_to_f32(u32 lo16) {
    return __uint_as_float(lo16 << 16);
}

__global__ __launch_bounds__(256) void zero4_kernel(float4* __restrict__ p, int n4) {
    int i = blockIdx.x * 256 + threadIdx.x;
    if (i < n4) p[i] = make_float4(0.f, 0.f, 0.f, 0.f);
}

__global__ __launch_bounds__(256) void hist_kernel(const int* __restrict__ dst,
                                                   int* __restrict__ deg, int E) {
    int e = blockIdx.x * 256 + threadIdx.x;
    if (e < E) atomicAdd(&deg[dst[e]], 1);
}

__global__ __launch_bounds__(256) void scan_reduce(const int* __restrict__ v,
                                                   int* __restrict__ bsums, int n) {
    __shared__ int sh[256];
    int i = blockIdx.x * 256 + threadIdx.x;
    sh[threadIdx.x] = (i < n) ? v[i] : 0;
    __syncthreads();
    for (int off = 128; off > 0; off >>= 1) {
        if (threadIdx.x < off) sh[threadIdx.x] += sh[threadIdx.x + off];
        __syncthreads();
    }
    if (threadIdx.x == 0) bsums[blockIdx.x] = sh[0];
}

__global__ __launch_bounds__(256) void scan_sums(int* __restrict__ bsums, int nb) {
    __shared__ int sh[256];
    int t = threadIdx.x;
    int val = (t < nb) ? bsums[t] : 0;
    sh[t] = val;
    __syncthreads();
    for (int off = 1; off < 256; off <<= 1) {
        int v = (t >= off) ? sh[t - off] : 0;
        __syncthreads();
        sh[t] += v;
        __syncthreads();
    }
    if (t < nb) bsums[t] = sh[t] - val;
}

__global__ __launch_bounds__(256) void scan_final(int* __restrict__ v,
                                                  const int* __restrict__ bsums, int n) {
    __shared__ int sh[256];
    int t = threadIdx.x;
    int i = blockIdx.x * 256 + t;
    int val = (i < n) ? v[i] : 0;
    sh[t] = val;
    __syncthreads();
    for (int off = 1; off < 256; off <<= 1) {
        int x = (t >= off) ? sh[t - off] : 0;
        __syncthreads();
        sh[t] += x;
        __syncthreads();
    }
    int excl = sh[t] - val + bsums[blockIdx.x];
    if (i < n) v[i] = excl;
    if (i == n - 1) v[n] = excl + val;
}

__global__ __launch_bounds__(256) void fill_kernel(const int* __restrict__ src,
                                                   const int* __restrict__ dst,
                                                   const int* __restrict__ row_start,
                                                   int* __restrict__ cursor,
                                                   int* __restrict__ csr_src, int E) {
    int e = blockIdx.x * 256 + threadIdx.x;
    if (e < E) {
        int d = dst[e];
        int pos = row_start[d] + atomicAdd(&cursor[d], 1);
        csr_src[pos] = src[e];
    }
}

// f32 [n8*8] -> bf16, 8 elems/thread
__global__ __launch_bounds__(256) void convert_bf16(const float* __restrict__ in,
                                                    u16* __restrict__ out, int n8) {
    int i = blockIdx.x * 256 + threadIdx.x;
    if (i >= n8) return;
    const float4* p = (const float4*)in + (size_t)i * 2;
    float4 v0 = p[0], v1 = p[1];
    uint4 o;
    o.x = (u32)f32_to_bf16(v0.x) | ((u32)f32_to_bf16(v0.y) << 16);
    o.y = (u32)f32_to_bf16(v0.z) | ((u32)f32_to_bf16(v0.w) << 16);
    o.z = (u32)f32_to_bf16(v1.x) | ((u32)f32_to_bf16(v1.y) << 16);
    o.w = (u32)f32_to_bf16(v1.z) | ((u32)f32_to_bf16(v1.w) << 16);
    ((uint4*)out)[i] = o;
}

// W [K][N] f32 -> WT [N][K] bf16, 32x32 tiles
__global__ __launch_bounds__(256) void transpose_w(const float* __restrict__ W,
                                                   u16* __restrict__ WT,
                                                   int K, int N) {
    __shared__ float t[32][33];
    int n0 = blockIdx.x * 32, k0 = blockIdx.y * 32;
    int c = threadIdx.x & 31, r0 = threadIdx.x >> 5;
    for (int r = r0; r < 32; r += 8)
        t[r][c] = W[(size_t)(k0 + r) * N + n0 + c];
    __syncthreads();
    for (int r = r0; r < 32; r += 8)
        WT[(size_t)(n0 + r) * K + k0 + c] = f32_to_bf16(t[c][r]);
}

// One wave per node: mean of neighbor bf16 rows, fp32 accum, bf16 out.
__global__ __launch_bounds__(256) void gather_mean_bf16(const u16* __restrict__ X,
                                                        const int* __restrict__ row_start,
                                                        const int* __restrict__ csr_src,
                                                        u16* __restrict__ agg, int M) {
    int node = (blockIdx.x * 256 + threadIdx.x) >> 6;
    int lane = threadIdx.x & 63;
    if (node >= M) return;
    int beg = row_start[node], end = row_start[node + 1];
    float a[8] = {0.f, 0.f, 0.f, 0.f, 0.f, 0.f, 0.f, 0.f};
    for (int c = beg; c < end; c += 64) {
        int nb = min(64, end - c);
        int eid = (lane < nb) ? csr_src[c + lane] : 0;
        for (int i = 0; i < nb; ++i) {
            int s = __shfl(eid, i);
            uint4 v = ((const uint4*)(X + (size_t)s * 512))[lane];
            a[0] += bf16_to_f32(v.x & 0xffffu); a[1] += bf16_to_f32(v.x >> 16);
            a[2] += bf16_to_f32(v.y & 0xffffu); a[3] += bf16_to_f32(v.y >> 16);
            a[4] += bf16_to_f32(v.z & 0xffffu); a[5] += bf16_to_f32(v.z >> 16);
            a[6] += bf16_to_f32(v.w & 0xffffu); a[7] += bf16_to_f32(v.w >> 16);
        }
    }
    float inv = 1.0f / fmaxf((float)(end - beg), 1.0f);
    uint4 o;
    o.x = (u32)f32_to_bf16(a[0] * inv) | ((u32)f32_to_bf16(a[1] * inv) << 16);
    o.y = (u32)f32_to_bf16(a[2] * inv) | ((u32)f32_to_bf16(a[3] * inv) << 16);
    o.z = (u32)f32_to_bf16(a[4] * inv) | ((u32)f32_to_bf16(a[5] * inv) << 16);
    o.w = (u32)f32_to_bf16(a[6] * inv) | ((u32)f32_to_bf16(a[7] * inv) << 16);
    ((uint4*)(agg + (size_t)node * 512))[lane] = o;
}

// C[M,N] = A1@B1T' + A2@B2T' + bias (B*T stored [N][512]), optional relu.
// 128x128 tile, fused K=1024, double-buffered LDS, ONE barrier/iter,
// prefetch issued after the barrier (stays in flight through the MFMAs).
__global__ __launch_bounds__(256) void gemm_bf16(
    const u16* __restrict__ A1, const u16* __restrict__ A2,
    const u16* __restrict__ B1T, const u16* __restrict__ B2T,
    const float* __restrict__ bias,
    u16* __restrict__ Cb, float* __restrict__ Cf,
    int M, int N, int relu, int nStrips, int nCols) {
    __shared__ u16 As[2][4096];  // [buf][kq*128 + row granules of 8 bf16]
    __shared__ u16 Bs[2][4096];

    int strip, colt;
    if (nCols == 4) {
        int b = blockIdx.x;
        int g = b >> 5, w5 = b & 31;
        strip = g * 8 + (w5 & 7);   // 4 col-tiles of a strip share b%8 -> same XCD
        colt = w5 >> 3;
        if (strip >= nStrips) return;
    } else {
        strip = blockIdx.x;
        colt = 0;
    }
    const int row0 = strip * 128, col0 = colt * 128;

    const int t = threadIdx.x;
    const int w = t >> 6, lane = t & 63;
    const int wm = (w >> 1) * 64, wn = (w & 1) * 64;
    const int l15 = lane & 15, kq = lane >> 4;

    floatx4 acc[4][4];
#pragma unroll
    for (int i = 0; i < 4; ++i)
#pragma unroll
        for (int j = 0; j < 4; ++j) acc[i][j] = floatx4{0.f, 0.f, 0.f, 0.f};

    // Per-thread staging addresses (K stride fixed 512). Wave w owns kq-chunk w.
    const size_t aoff0 = (size_t)min(row0 + lane, M - 1) * 512 + w * 8;
    const size_t aoff1 = (size_t)min(row0 + 64 + lane, M - 1) * 512 + w * 8;
    const size_t boff0 = (size_t)(col0 + lane) * 512 + w * 8;
    const size_t boff1 = (size_t)(col0 + 64 + lane) * 512 + w * 8;
    const int gA0 = (w * 128 + lane) * 8;        // LDS granule offsets (u16 idx)
    const int gA1 = (w * 128 + 64 + lane) * 8;

    uint4 ra0, ra1, rb0, rb1;
    auto loadTile = [&](int it) {
        int k0 = it * 32;
        const u16* Ap = (k0 < 512) ? A1 : A2;
        const u16* Bp = (k0 < 512) ? B1T : B2T;
        int eff = k0 & 511;
        ra0 = *(const uint4*)(Ap + aoff0 + eff);
        ra1 = *(const uint4*)(Ap + aoff1 + eff);
        rb0 = *(const uint4*)(Bp + boff0 + eff);
        rb1 = *(const uint4*)(Bp + boff1 + eff);
    };

    loadTile(0);
    for (int it = 0; it < 32; ++it) {
        const int buf = it & 1;
        // store staged regs (compiler waits vmcnt here; loads were overlapped
        // with the previous iteration's MFMAs)
        *(uint4*)&As[buf][gA0] = ra0;
        *(uint4*)&As[buf][gA1] = ra1;
        *(uint4*)&Bs[buf][gA0] = rb0;
        *(uint4*)&Bs[buf][gA1] = rb1;
        __syncthreads();   // buffer visible; also guards buf reuse (see header)
        if (it + 1 < 32) loadTile(it + 1);  // issued AFTER barrier: not drained

        const short8* Asv = (const short8*)&As[buf][0];
        const short8* Bsv = (const short8*)&Bs[buf][0];
        short8 a[4], b[4];
#pragma unroll
        for (int mt = 0; mt < 4; ++mt)
            a[mt] = Asv[kq * 128 + wm + mt * 16 + l15];
#pragma unroll
        for (int nt = 0; nt < 4; ++nt)
            b[nt] = Bsv[kq * 128 + wn + nt * 16 + l15];
#pragma unroll
        for (int mt = 0; mt < 4; ++mt)
#pragma unroll
            for (int nt = 0; nt < 4; ++nt)
                acc[mt][nt] = __builtin_amdgcn_mfma_f32_16x16x32_bf16(
                    a[mt], b[nt], acc[mt][nt], 0, 0, 0);
    }

    // Epilogue. C/D: col = lane&15, row = (lane>>4)*4 + reg  [m89/m91]
#pragma unroll
    for (int nt = 0; nt < 4; ++nt) {
        int col = col0 + wn + nt * 16 + l15;
        float bv = bias[col];
#pragma unroll
        for (int mt = 0; mt < 4; ++mt) {
#pragma unroll
            for (int r = 0; r < 4; ++r) {
                int row = row0 + wm + mt * 16 + kq * 4 + r;
                if (row >= M) continue;
                float v = acc[mt][nt][r] + bv;
                if (relu) v = fmaxf(v, 0.f);
                if (Cf) Cf[(size_t)row * N + col] = v;
                else Cb[(size_t)row * N + col] = f32_to_bf16(v);
            }
        }
    }
}

// In-place log_softmax over rows of 128; one wave per row.
__global__ __launch_bounds__(256) void logsoftmax128(float* __restrict__ out, int M) {
    int row = blockIdx.x * 4 + (threadIdx.x >> 6);
    int lane = threadIdx.x & 63;
    if (row >= M) return;
    float* p = out + (size_t)row * 128;
    float a = p[lane];
    float b = p[lane + 64];
    float m = fmaxf(a, b);
#pragma unroll
    for (int off = 32; off > 0; off >>= 1) m = fmaxf(m, __shfl_xor(m, off));
    float s = expf(a - m) + expf(b - m);
#pragma unroll
    for (int off = 32; off > 0; off >>= 1) s += __shfl_xor(s, off);
    float ls = m + logf(s);
    p[lane] = a - ls;
    p[lane + 64] = b - ls;
}

extern "C" void kernel_launch(void* const* d_in, const int* in_sizes, int n_in,
                              void* d_out, int out_size, void* d_ws, size_t ws_size,
                              hipStream_t stream) {
    const float* x    = (const float*)d_in[0];
    const int*   ei   = (const int*)d_in[1];
    const float* W1_l = (const float*)d_in[2];
    const float* b1   = (const float*)d_in[3];
    const float* W1_r = (const float*)d_in[4];
    const float* W2_l = (const float*)d_in[5];
    const float* b2   = (const float*)d_in[6];
    const float* W2_r = (const float*)d_in[7];
    const float* W3_l = (const float*)d_in[8];
    const float* b3   = (const float*)d_in[9];
    const float* W3_r = (const float*)d_in[10];
    float* out = (float*)d_out;

    const int* src = ei;
    const int* dst = ei + N_EDGES;

    // Workspace layout (bytes from base):
    char* base = (char*)d_ws;
    int* row_start = (int*)(base);                    // 50052 ints
    int* cursor    = (int*)(base + 200208);           // 50052 ints
    int* bsums     = (int*)(base + 400416);           // 512 ints
    int* csr_src   = (int*)(base + 402464);           // 400000 ints -> end 2002464
    u16* xb   = (u16*)(base + 2002464);               // 25.6M bf16
    u16* aggb = (u16*)(base + 53202464);
    u16* h1b  = (u16*)(base + 104402464);
    u16* h2b  = (u16*)(base + 155602464);
    u16* w1lT = (u16*)(base + 206802464);             // [512][512]
    u16* w1rT = (u16*)(base + 207326752);
    u16* w2lT = (u16*)(base + 207851040);
    u16* w2rT = (u16*)(base + 208375328);
    u16* w3lT = (u16*)(base + 208899616);             // [128][512]
    u16* w3rT = (u16*)(base + 209030688);             // end 209161760

    const int E = N_EDGES, M = N_NODES;
    const int nblk = (M + 255) / 256;

    // ---- CSR build ----
    zero4_kernel<<<(25154 + 255) / 256, 256, 0, stream>>>((float4*)d_ws, 25154);
    hist_kernel<<<(E + 255) / 256, 256, 0, stream>>>(dst, row_start, E);
    scan_reduce<<<nblk, 256, 0, stream>>>(row_start, bsums, M);
    scan_sums<<<1, 256, 0, stream>>>(bsums, nblk);
    scan_final<<<nblk, 256, 0, stream>>>(row_start, bsums, M);
    fill_kernel<<<(E + 255) / 256, 256, 0, stream>>>(src, dst, row_start, cursor,
                                                     csr_src, E);

    // ---- conversions ----
    convert_bf16<<<(3200000 + 255) / 256, 256, 0, stream>>>(x, xb, 3200000);
    transpose_w<<<dim3(16, 16), 256, 0, stream>>>(W1_l, w1lT, 512, 512);
    transpose_w<<<dim3(16, 16), 256, 0, stream>>>(W1_r, w1rT, 512, 512);
    transpose_w<<<dim3(16, 16), 256, 0, stream>>>(W2_l, w2lT, 512, 512);
    transpose_w<<<dim3(16, 16), 256, 0, stream>>>(W2_r, w2rT, 512, 512);
    transpose_w<<<dim3(4, 16), 256, 0, stream>>>(W3_l, w3lT, 512, 128);
    transpose_w<<<dim3(4, 16), 256, 0, stream>>>(W3_r, w3rT, 512, 128);

    const int gather_blocks = (M * 64 + 255) / 256;
    const int nStrips = (M + 127) / 128;                 // 391
    const int bigGrid = ((nStrips + 7) / 8) * 32;        // 1568 (swizzled)

    // ---- layer 1 ----
    gather_mean_bf16<<<gather_blocks, 256, 0, stream>>>(xb, row_start, csr_src, aggb, M);
    gemm_bf16<<<bigGrid, 256, 0, stream>>>(aggb, xb, w1lT, w1rT, b1,
                                           h1b, nullptr, M, 512, 1, nStrips, 4);
    // ---- layer 2 ----
    gather_mean_bf16<<<gather_blocks, 256, 0, stream>>>(h1b, row_start, csr_src, aggb, M);
    gemm_bf16<<<bigGrid, 256, 0, stream>>>(aggb, h1b, w2lT, w2rT, b2,
                                           h2b, nullptr, M, 512, 1, nStrips, 4);
    // ---- layer 3 ----
    gather_mean_bf16<<<gather_blocks, 256, 0, stream>>>(h2b, row_start, csr_src, aggb, M);
    gemm_bf16<<<nStrips, 256, 0, stream>>>(aggb, h2b, w3lT, w3rT, b3,
                                           nullptr, out, M, 128, 0, nStrips, 1);

    logsoftmax128<<<(M + 3) / 4, 256, 0, stream>>>(out, M);
}

// Round 7
// 709.878 us; speedup vs baseline: 1.5157x; 1.2646x over previous
//
#include <hip/hip_runtime.h>
#include <hip/hip_bf16.h>

// GraphSAGE 3-layer, N=50000 nodes, E=400000 edges, dims 512->512->512->128.
// Round 6 -> 7: r3/r4/r6 GEMMs all hit 205us -- the shared limiter is the
// L1/TA line-request rate (~1 line-req/cyc/CU): staging loads had 1 lane per
// row (64 distinct 64B lines per instruction, zero coalescing) and the
// epilogue issued 64 scalar u16 stores per thread. This round:
//  - staging maps 4 consecutive lanes to one row (16B each) -> 16 lines/instr
//    (2x fewer load line-requests); LDS is row-major, rows padded to 80B
//    (20 words -> ~2-way bank aliasing, free per m136)
//  - swapped-operand MFMA: acc = mfma(b_frag, a_frag, acc) yields C^T register
//    layout (lane=C-row, reg=C-col) -> 4 consecutive cols per frag -> packed
//    8B stores (4x fewer store requests, full-line write combining)

#define N_NODES 50000
#define N_EDGES 400000

typedef unsigned short u16;
typedef unsigned int u32;
typedef __attribute__((ext_vector_type(8))) short short8;
typedef __attribute__((ext_vector_type(4))) float floatx4;

__device__ __forceinline__ u16 f32_to_bf16(float f) {
    u32 u = __float_as_uint(f);
    u32 r = 0x7FFFu + ((u >> 16) & 1u);
    return (u16)((u + r) >> 16);
}
__device__ __forceinline__ float bf16_to_f32(u32 lo16) {
    return __uint_as_float(lo16 << 16);
}

__global__ __launch_bounds__(256) void zero4_kernel(float4* __restrict__ p, int n4) {
    int i = blockIdx.x * 256 + threadIdx.x;
    if (i < n4) p[i] = make_float4(0.f, 0.f, 0.f, 0.f);
}

__global__ __launch_bounds__(256) void hist_kernel(const int* __restrict__ dst,
                                                   int* __restrict__ deg, int E) {
    int e = blockIdx.x * 256 + threadIdx.x;
    if (e < E) atomicAdd(&deg[dst[e]], 1);
}

__global__ __launch_bounds__(256) void scan_reduce(const int* __restrict__ v,
                                                   int* __restrict__ bsums, int n) {
    __shared__ int sh[256];
    int i = blockIdx.x * 256 + threadIdx.x;
    sh[threadIdx.x] = (i < n) ? v[i] : 0;
    __syncthreads();
    for (int off = 128; off > 0; off >>= 1) {
        if (threadIdx.x < off) sh[threadIdx.x] += sh[threadIdx.x + off];
        __syncthreads();
    }
    if (threadIdx.x == 0) bsums[blockIdx.x] = sh[0];
}

__global__ __launch_bounds__(256) void scan_sums(int* __restrict__ bsums, int nb) {
    __shared__ int sh[256];
    int t = threadIdx.x;
    int val = (t < nb) ? bsums[t] : 0;
    sh[t] = val;
    __syncthreads();
    for (int off = 1; off < 256; off <<= 1) {
        int v = (t >= off) ? sh[t - off] : 0;
        __syncthreads();
        sh[t] += v;
        __syncthreads();
    }
    if (t < nb) bsums[t] = sh[t] - val;
}

__global__ __launch_bounds__(256) void scan_final(int* __restrict__ v,
                                                  const int* __restrict__ bsums, int n) {
    __shared__ int sh[256];
    int t = threadIdx.x;
    int i = blockIdx.x * 256 + t;
    int val = (i < n) ? v[i] : 0;
    sh[t] = val;
    __syncthreads();
    for (int off = 1; off < 256; off <<= 1) {
        int x = (t >= off) ? sh[t - off] : 0;
        __syncthreads();
        sh[t] += x;
        __syncthreads();
    }
    int excl = sh[t] - val + bsums[blockIdx.x];
    if (i < n) v[i] = excl;
    if (i == n - 1) v[n] = excl + val;
}

__global__ __launch_bounds__(256) void fill_kernel(const int* __restrict__ src,
                                                   const int* __restrict__ dst,
                                                   const int* __restrict__ row_start,
                                                   int* __restrict__ cursor,
                                                   int* __restrict__ csr_src, int E) {
    int e = blockIdx.x * 256 + threadIdx.x;
    if (e < E) {
        int d = dst[e];
        int pos = row_start[d] + atomicAdd(&cursor[d], 1);
        csr_src[pos] = src[e];
    }
}

// f32 [n8*8] -> bf16, 8 elems/thread
__global__ __launch_bounds__(256) void convert_bf16(const float* __restrict__ in,
                                                    u16* __restrict__ out, int n8) {
    int i = blockIdx.x * 256 + threadIdx.x;
    if (i >= n8) return;
    const float4* p = (const float4*)in + (size_t)i * 2;
    float4 v0 = p[0], v1 = p[1];
    uint4 o;
    o.x = (u32)f32_to_bf16(v0.x) | ((u32)f32_to_bf16(v0.y) << 16);
    o.y = (u32)f32_to_bf16(v0.z) | ((u32)f32_to_bf16(v0.w) << 16);
    o.z = (u32)f32_to_bf16(v1.x) | ((u32)f32_to_bf16(v1.y) << 16);
    o.w = (u32)f32_to_bf16(v1.z) | ((u32)f32_to_bf16(v1.w) << 16);
    ((uint4*)out)[i] = o;
}

// W [K][N] f32 -> WT [N][K] bf16, 32x32 tiles
__global__ __launch_bounds__(256) void transpose_w(const float* __restrict__ W,
                                                   u16* __restrict__ WT,
                                                   int K, int N) {
    __shared__ float t[32][33];
    int n0 = blockIdx.x * 32, k0 = blockIdx.y * 32;
    int c = threadIdx.x & 31, r0 = threadIdx.x >> 5;
    for (int r = r0; r < 32; r += 8)
        t[r][c] = W[(size_t)(k0 + r) * N + n0 + c];
    __syncthreads();
    for (int r = r0; r < 32; r += 8)
        WT[(size_t)(n0 + r) * K + k0 + c] = f32_to_bf16(t[c][r]);
}

// One wave per node: mean of neighbor bf16 rows, fp32 accum, bf16 out.
__global__ __launch_bounds__(256) void gather_mean_bf16(const u16* __restrict__ X,
                                                        const int* __restrict__ row_start,
                                                        const int* __restrict__ csr_src,
                                                        u16* __restrict__ agg, int M) {
    int node = (blockIdx.x * 256 + threadIdx.x) >> 6;
    int lane = threadIdx.x & 63;
    if (node >= M) return;
    int beg = row_start[node], end = row_start[node + 1];
    float a[8] = {0.f, 0.f, 0.f, 0.f, 0.f, 0.f, 0.f, 0.f};
    for (int c = beg; c < end; c += 64) {
        int nb = min(64, end - c);
        int eid = (lane < nb) ? csr_src[c + lane] : 0;
        for (int i = 0; i < nb; ++i) {
            int s = __shfl(eid, i);
            uint4 v = ((const uint4*)(X + (size_t)s * 512))[lane];
            a[0] += bf16_to_f32(v.x & 0xffffu); a[1] += bf16_to_f32(v.x >> 16);
            a[2] += bf16_to_f32(v.y & 0xffffu); a[3] += bf16_to_f32(v.y >> 16);
            a[4] += bf16_to_f32(v.z & 0xffffu); a[5] += bf16_to_f32(v.z >> 16);
            a[6] += bf16_to_f32(v.w & 0xffffu); a[7] += bf16_to_f32(v.w >> 16);
        }
    }
    float inv = 1.0f / fmaxf((float)(end - beg), 1.0f);
    uint4 o;
    o.x = (u32)f32_to_bf16(a[0] * inv) | ((u32)f32_to_bf16(a[1] * inv) << 16);
    o.y = (u32)f32_to_bf16(a[2] * inv) | ((u32)f32_to_bf16(a[3] * inv) << 16);
    o.z = (u32)f32_to_bf16(a[4] * inv) | ((u32)f32_to_bf16(a[5] * inv) << 16);
    o.w = (u32)f32_to_bf16(a[6] * inv) | ((u32)f32_to_bf16(a[7] * inv) << 16);
    ((uint4*)(agg + (size_t)node * 512))[lane] = o;
}

#define LDSROW 40  // u16 per LDS row (80 B padded; 64 B used)

// C[M,N] = A1@B1T' + A2@B2T' + bias (B*T stored [N][512]), optional relu.
// 128x128 tile, fused K=1024, dbuf LDS, 1 barrier/iter, coalesced staging
// (4 lanes per row), swapped-operand MFMA -> C^T reg layout -> 8B stores.
__global__ __launch_bounds__(256) void gemm_bf16(
    const u16* __restrict__ A1, const u16* __restrict__ A2,
    const u16* __restrict__ B1T, const u16* __restrict__ B2T,
    const float* __restrict__ bias,
    u16* __restrict__ Cb, float* __restrict__ Cf,
    int M, int N, int relu, int nStrips, int nCols) {
    __shared__ u16 As[2][128 * LDSROW];  // 10 KB per buf
    __shared__ u16 Bs[2][128 * LDSROW];

    int strip, colt;
    if (nCols == 4) {
        int b = blockIdx.x;
        int g = b >> 5, w5 = b & 31;
        strip = g * 8 + (w5 & 7);   // 4 col-tiles of a strip share b%8 -> same XCD
        colt = w5 >> 3;
        if (strip >= nStrips) return;
    } else {
        strip = blockIdx.x;
        colt = 0;
    }
    const int row0 = strip * 128, col0 = colt * 128;

    const int t = threadIdx.x;
    const int w = t >> 6, lane = t & 63;
    const int wm = (w >> 1) * 64, wn = (w & 1) * 64;
    const int l15 = lane & 15, kq = lane >> 4;

    floatx4 acc[4][4];
#pragma unroll
    for (int i = 0; i < 4; ++i)
#pragma unroll
        for (int j = 0; j < 4; ++j) acc[i][j] = floatx4{0.f, 0.f, 0.f, 0.f};

    // Coalesced staging: thread t handles rows (t>>2) and (t>>2)+64,
    // 16B chunk (t&3) of the row's 64B k-slice. 4 lanes share a 64B line.
    const int sr = t >> 2;            // 0..63
    const int sce = (t & 3) * 8;      // element offset (16B chunks)
    const size_t aoffS0 = (size_t)min(row0 + sr, M - 1) * 512 + sce;
    const size_t aoffS1 = (size_t)min(row0 + 64 + sr, M - 1) * 512 + sce;
    const size_t boffS0 = (size_t)(col0 + sr) * 512 + sce;
    const size_t boffS1 = (size_t)(col0 + 64 + sr) * 512 + sce;
    const int ldsS0 = sr * LDSROW + sce;
    const int ldsS1 = (sr + 64) * LDSROW + sce;

    uint4 ra0, ra1, rb0, rb1;
    auto loadTile = [&](int it) {
        int k0 = it * 32;
        const u16* Ap = (k0 < 512) ? A1 : A2;
        const u16* Bp = (k0 < 512) ? B1T : B2T;
        int eff = k0 & 511;
        ra0 = *(const uint4*)(Ap + aoffS0 + eff);
        ra1 = *(const uint4*)(Ap + aoffS1 + eff);
        rb0 = *(const uint4*)(Bp + boffS0 + eff);
        rb1 = *(const uint4*)(Bp + boffS1 + eff);
    };

    loadTile(0);
    for (int it = 0; it < 32; ++it) {
        const int buf = it & 1;
        *(uint4*)&As[buf][ldsS0] = ra0;
        *(uint4*)&As[buf][ldsS1] = ra1;
        *(uint4*)&Bs[buf][ldsS0] = rb0;
        *(uint4*)&Bs[buf][ldsS1] = rb1;
        __syncthreads();
        if (it + 1 < 32) loadTile(it + 1);  // overlaps the MFMAs below

        short8 a[4], b[4];
#pragma unroll
        for (int mt = 0; mt < 4; ++mt)
            a[mt] = *(const short8*)&As[buf][(wm + mt * 16 + l15) * LDSROW + kq * 8];
#pragma unroll
        for (int nt = 0; nt < 4; ++nt)
            b[nt] = *(const short8*)&Bs[buf][(wn + nt * 16 + l15) * LDSROW + kq * 8];
        // Swapped operands: D = C^T; lane l15 = C-row, reg = C-col (kq*4+r)
#pragma unroll
        for (int mt = 0; mt < 4; ++mt)
#pragma unroll
            for (int nt = 0; nt < 4; ++nt)
                acc[mt][nt] = __builtin_amdgcn_mfma_f32_16x16x32_bf16(
                    b[nt], a[mt], acc[mt][nt], 0, 0, 0);
    }

    // Epilogue (C^T layout): row = wm+mt*16+l15, cols = wn+nt*16+kq*4 .. +3
#pragma unroll
    for (int mt = 0; mt < 4; ++mt) {
        int row = row0 + wm + mt * 16 + l15;
        if (row >= M) continue;
#pragma unroll
        for (int nt = 0; nt < 4; ++nt) {
            int c0 = col0 + wn + nt * 16 + kq * 4;
            float4 bb = *(const float4*)(bias + c0);
            float v0 = acc[mt][nt][0] + bb.x;
            float v1 = acc[mt][nt][1] + bb.y;
            float v2 = acc[mt][nt][2] + bb.z;
            float v3 = acc[mt][nt][3] + bb.w;
            if (relu) {
                v0 = fmaxf(v0, 0.f); v1 = fmaxf(v1, 0.f);
                v2 = fmaxf(v2, 0.f); v3 = fmaxf(v3, 0.f);
            }
            if (Cf) {
                *(float4*)(Cf + (size_t)row * N + c0) = make_float4(v0, v1, v2, v3);
            } else {
                uint2 o;
                o.x = (u32)f32_to_bf16(v0) | ((u32)f32_to_bf16(v1) << 16);
                o.y = (u32)f32_to_bf16(v2) | ((u32)f32_to_bf16(v3) << 16);
                *(uint2*)(Cb + (size_t)row * N + c0) = o;
            }
        }
    }
}

// In-place log_softmax over rows of 128; one wave per row.
__global__ __launch_bounds__(256) void logsoftmax128(float* __restrict__ out, int M) {
    int row = blockIdx.x * 4 + (threadIdx.x >> 6);
    int lane = threadIdx.x & 63;
    if (row >= M) return;
    float* p = out + (size_t)row * 128;
    float a = p[lane];
    float b = p[lane + 64];
    float m = fmaxf(a, b);
#pragma unroll
    for (int off = 32; off > 0; off >>= 1) m = fmaxf(m, __shfl_xor(m, off));
    float s = expf(a - m) + expf(b - m);
#pragma unroll
    for (int off = 32; off > 0; off >>= 1) s += __shfl_xor(s, off);
    float ls = m + logf(s);
    p[lane] = a - ls;
    p[lane + 64] = b - ls;
}

extern "C" void kernel_launch(void* const* d_in, const int* in_sizes, int n_in,
                              void* d_out, int out_size, void* d_ws, size_t ws_size,
                              hipStream_t stream) {
    const float* x    = (const float*)d_in[0];
    const int*   ei   = (const int*)d_in[1];
    const float* W1_l = (const float*)d_in[2];
    const float* b1   = (const float*)d_in[3];
    const float* W1_r = (const float*)d_in[4];
    const float* W2_l = (const float*)d_in[5];
    const float* b2   = (const float*)d_in[6];
    const float* W2_r = (const float*)d_in[7];
    const float* W3_l = (const float*)d_in[8];
    const float* b3   = (const float*)d_in[9];
    const float* W3_r = (const float*)d_in[10];
    float* out = (float*)d_out;

    const int* src = ei;
    const int* dst = ei + N_EDGES;

    // Workspace layout (bytes from base):
    char* base = (char*)d_ws;
    int* row_start = (int*)(base);                    // 50052 ints
    int* cursor    = (int*)(base + 200208);           // 50052 ints
    int* bsums     = (int*)(base + 400416);           // 512 ints
    int* csr_src   = (int*)(base + 402464);           // 400000 ints -> end 2002464
    u16* xb   = (u16*)(base + 2002464);               // 25.6M bf16
    u16* aggb = (u16*)(base + 53202464);
    u16* h1b  = (u16*)(base + 104402464);
    u16* h2b  = (u16*)(base + 155602464);
    u16* w1lT = (u16*)(base + 206802464);             // [512][512]
    u16* w1rT = (u16*)(base + 207326752);
    u16* w2lT = (u16*)(base + 207851040);
    u16* w2rT = (u16*)(base + 208375328);
    u16* w3lT = (u16*)(base + 208899616);             // [128][512]
    u16* w3rT = (u16*)(base + 209030688);             // end 209161760

    const int E = N_EDGES, M = N_NODES;
    const int nblk = (M + 255) / 256;

    // ---- CSR build ----
    zero4_kernel<<<(25154 + 255) / 256, 256, 0, stream>>>((float4*)d_ws, 25154);
    hist_kernel<<<(E + 255) / 256, 256, 0, stream>>>(dst, row_start, E);
    scan_reduce<<<nblk, 256, 0, stream>>>(row_start, bsums, M);
    scan_sums<<<1, 256, 0, stream>>>(bsums, nblk);
    scan_final<<<nblk, 256, 0, stream>>>(row_start, bsums, M);
    fill_kernel<<<(E + 255) / 256, 256, 0, stream>>>(src, dst, row_start, cursor,
                                                     csr_src, E);

    // ---- conversions ----
    convert_bf16<<<(3200000 + 255) / 256, 256, 0, stream>>>(x, xb, 3200000);
    transpose_w<<<dim3(16, 16), 256, 0, stream>>>(W1_l, w1lT, 512, 512);
    transpose_w<<<dim3(16, 16), 256, 0, stream>>>(W1_r, w1rT, 512, 512);
    transpose_w<<<dim3(16, 16), 256, 0, stream>>>(W2_l, w2lT, 512, 512);
    transpose_w<<<dim3(16, 16), 256, 0, stream>>>(W2_r, w2rT, 512, 512);
    transpose_w<<<dim3(4, 16), 256, 0, stream>>>(W3_l, w3lT, 512, 128);
    transpose_w<<<dim3(4, 16), 256, 0, stream>>>(W3_r, w3rT, 512, 128);

    const int gather_blocks = (M * 64 + 255) / 256;
    const int nStrips = (M + 127) / 128;                 // 391
    const int bigGrid = ((nStrips + 7) / 8) * 32;        // 1568 (swizzled)

    // ---- layer 1 ----
    gather_mean_bf16<<<gather_blocks, 256, 0, stream>>>(xb, row_start, csr_src, aggb, M);
    gemm_bf16<<<bigGrid, 256, 0, stream>>>(aggb, xb, w1lT, w1rT, b1,
                                           h1b, nullptr, M, 512, 1, nStrips, 4);
    // ---- layer 2 ----
    gather_mean_bf16<<<gather_blocks, 256, 0, stream>>>(h1b, row_start, csr_src, aggb, M);
    gemm_bf16<<<bigGrid, 256, 0, stream>>>(aggb, h1b, w2lT, w2rT, b2,
                                           h2b, nullptr, M, 512, 1, nStrips, 4);
    // ---- layer 3 ----
    gather_mean_bf16<<<gather_blocks, 256, 0, stream>>>(h2b, row_start, csr_src, aggb, M);
    gemm_bf16<<<nStrips, 256, 0, stream>>>(aggb, h2b, w3lT, w3rT, b3,
                                           nullptr, out, M, 128, 0, nStrips, 1);

    logsoftmax128<<<(M + 3) / 4, 256, 0, stream>>>(out, M);
}

// Round 8
// 660.100 us; speedup vs baseline: 1.6300x; 1.0754x over previous
//
#include <hip/hip_runtime.h>
#include <hip/hip_bf16.h>

// GraphSAGE 3-layer, N=50000 nodes, E=400000 edges, dims 512->512->512->128.
// Round 7 -> 8:
//  (a) XOR-swizzled LDS (64B rows, chunk c^=(row>>1)&3): kills the 1.28e7
//      bank conflicts the 80B-pad layout introduced; reads are 2-way (free),
//      writes conflict-free.
//  (b) transform-before-aggregate: mean(x_j)@W_l == mean(x_j@W_l), so each
//      layer is ONE single-pass GEMM Y=[Yl|Yr]=h@[W_l|W_r] (A read once, no
//      bias/relu in GEMM) followed by a fused gather-add:
//      h' = relu(mean(Yl[src]) + Yr + b). Layer 3 gathers 128-d rows (4x less
//      random traffic) and fuses log_softmax (removes 51MB round-trip).

#define N_NODES 50000
#define N_EDGES 400000

typedef unsigned short u16;
typedef unsigned int u32;
typedef __attribute__((ext_vector_type(8))) short short8;
typedef __attribute__((ext_vector_type(4))) float floatx4;

__device__ __forceinline__ u16 f32_to_bf16(float f) {
    u32 u = __float_as_uint(f);
    u32 r = 0x7FFFu + ((u >> 16) & 1u);
    return (u16)((u + r) >> 16);
}
__device__ __forceinline__ float bf16_to_f32(u32 lo16) {
    return __uint_as_float(lo16 << 16);
}

__global__ __launch_bounds__(256) void zero4_kernel(float4* __restrict__ p, int n4) {
    int i = blockIdx.x * 256 + threadIdx.x;
    if (i < n4) p[i] = make_float4(0.f, 0.f, 0.f, 0.f);
}

__global__ __launch_bounds__(256) void hist_kernel(const int* __restrict__ dst,
                                                   int* __restrict__ deg, int E) {
    int e = blockIdx.x * 256 + threadIdx.x;
    if (e < E) atomicAdd(&deg[dst[e]], 1);
}

__global__ __launch_bounds__(256) void scan_reduce(const int* __restrict__ v,
                                                   int* __restrict__ bsums, int n) {
    __shared__ int sh[256];
    int i = blockIdx.x * 256 + threadIdx.x;
    sh[threadIdx.x] = (i < n) ? v[i] : 0;
    __syncthreads();
    for (int off = 128; off > 0; off >>= 1) {
        if (threadIdx.x < off) sh[threadIdx.x] += sh[threadIdx.x + off];
        __syncthreads();
    }
    if (threadIdx.x == 0) bsums[blockIdx.x] = sh[0];
}

__global__ __launch_bounds__(256) void scan_sums(int* __restrict__ bsums, int nb) {
    __shared__ int sh[256];
    int t = threadIdx.x;
    int val = (t < nb) ? bsums[t] : 0;
    sh[t] = val;
    __syncthreads();
    for (int off = 1; off < 256; off <<= 1) {
        int v = (t >= off) ? sh[t - off] : 0;
        __syncthreads();
        sh[t] += v;
        __syncthreads();
    }
    if (t < nb) bsums[t] = sh[t] - val;
}

__global__ __launch_bounds__(256) void scan_final(int* __restrict__ v,
                                                  const int* __restrict__ bsums, int n) {
    __shared__ int sh[256];
    int t = threadIdx.x;
    int i = blockIdx.x * 256 + t;
    int val = (i < n) ? v[i] : 0;
    sh[t] = val;
    __syncthreads();
    for (int off = 1; off < 256; off <<= 1) {
        int x = (t >= off) ? sh[t - off] : 0;
        __syncthreads();
        sh[t] += x;
        __syncthreads();
    }
    int excl = sh[t] - val + bsums[blockIdx.x];
    if (i < n) v[i] = excl;
    if (i == n - 1) v[n] = excl + val;
}

__global__ __launch_bounds__(256) void fill_kernel(const int* __restrict__ src,
                                                   const int* __restrict__ dst,
                                                   const int* __restrict__ row_start,
                                                   int* __restrict__ cursor,
                                                   int* __restrict__ csr_src, int E) {
    int e = blockIdx.x * 256 + threadIdx.x;
    if (e < E) {
        int d = dst[e];
        int pos = row_start[d] + atomicAdd(&cursor[d], 1);
        csr_src[pos] = src[e];
    }
}

// f32 [n8*8] -> bf16, 8 elems/thread
__global__ __launch_bounds__(256) void convert_bf16(const float* __restrict__ in,
                                                    u16* __restrict__ out, int n8) {
    int i = blockIdx.x * 256 + threadIdx.x;
    if (i >= n8) return;
    const float4* p = (const float4*)in + (size_t)i * 2;
    float4 v0 = p[0], v1 = p[1];
    uint4 o;
    o.x = (u32)f32_to_bf16(v0.x) | ((u32)f32_to_bf16(v0.y) << 16);
    o.y = (u32)f32_to_bf16(v0.z) | ((u32)f32_to_bf16(v0.w) << 16);
    o.z = (u32)f32_to_bf16(v1.x) | ((u32)f32_to_bf16(v1.y) << 16);
    o.w = (u32)f32_to_bf16(v1.z) | ((u32)f32_to_bf16(v1.w) << 16);
    ((uint4*)out)[i] = o;
}

// W [K][N] f32 -> WT [N][K] bf16, 32x32 tiles
__global__ __launch_bounds__(256) void transpose_w(const float* __restrict__ W,
                                                   u16* __restrict__ WT,
                                                   int K, int N) {
    __shared__ float t[32][33];
    int n0 = blockIdx.x * 32, k0 = blockIdx.y * 32;
    int c = threadIdx.x & 31, r0 = threadIdx.x >> 5;
    for (int r = r0; r < 32; r += 8)
        t[r][c] = W[(size_t)(k0 + r) * N + n0 + c];
    __syncthreads();
    for (int r = r0; r < 32; r += 8)
        WT[(size_t)(n0 + r) * K + k0 + c] = f32_to_bf16(t[c][r]);
}

// C = A @ BT' (BT stored [N][512], k-contig), single pass K=512, bf16 out.
// 128x128 tile, dbuf LDS, 1 barrier/iter, coalesced staging, XOR swizzle,
// swapped-operand MFMA (C^T regs -> packed 8B stores).
// Output split: cols < split -> Cl (row stride split), else Cr (col-split).
__global__ __launch_bounds__(256) void gemm_bf16(
    const u16* __restrict__ A, const u16* __restrict__ BT,
    u16* __restrict__ Cl, u16* __restrict__ Cr,
    int M, int split, int nStrips, int nCols) {
    __shared__ u16 As[2][4096];  // 128 rows x 32 u16 (64B), XOR-swizzled chunks
    __shared__ u16 Bs[2][4096];

    const int grp = 8 * nCols;
    int b = blockIdx.x;
    int strip = (b / grp) * 8 + (b & 7);   // col-tiles of a strip share b%8 -> XCD
    int colt = (b % grp) >> 3;
    if (strip >= nStrips) return;
    const int row0 = strip * 128, col0 = colt * 128;

    const int t = threadIdx.x;
    const int w = t >> 6, lane = t & 63;
    const int wm = (w >> 1) * 64, wn = (w & 1) * 64;
    const int l15 = lane & 15, kq = lane >> 4;
    const int swz = (l15 >> 1) & 3;        // fragment-read swizzle bits

    floatx4 acc[4][4];
#pragma unroll
    for (int i = 0; i < 4; ++i)
#pragma unroll
        for (int j = 0; j < 4; ++j) acc[i][j] = floatx4{0.f, 0.f, 0.f, 0.f};

    // Coalesced staging: thread t -> rows sr, sr+64; 16B chunk (t&3).
    const int sr = t >> 2;
    const int sc = t & 3;
    const size_t aoffS0 = (size_t)min(row0 + sr, M - 1) * 512 + sc * 8;
    const size_t aoffS1 = (size_t)min(row0 + 64 + sr, M - 1) * 512 + sc * 8;
    const size_t boffS0 = (size_t)(col0 + sr) * 512 + sc * 8;
    const size_t boffS1 = (size_t)(col0 + 64 + sr) * 512 + sc * 8;
    const int swzS = (sr >> 1) & 3;        // same bits for sr and sr+64
    const int ldsS0 = sr * 32 + (sc ^ swzS) * 8;
    const int ldsS1 = (sr + 64) * 32 + (sc ^ swzS) * 8;

    uint4 ra0, ra1, rb0, rb1;
    auto loadTile = [&](int it) {
        int eff = it * 32;
        ra0 = *(const uint4*)(A + aoffS0 + eff);
        ra1 = *(const uint4*)(A + aoffS1 + eff);
        rb0 = *(const uint4*)(BT + boffS0 + eff);
        rb1 = *(const uint4*)(BT + boffS1 + eff);
    };

    loadTile(0);
    for (int it = 0; it < 16; ++it) {
        const int buf = it & 1;
        *(uint4*)&As[buf][ldsS0] = ra0;
        *(uint4*)&As[buf][ldsS1] = ra1;
        *(uint4*)&Bs[buf][ldsS0] = rb0;
        *(uint4*)&Bs[buf][ldsS1] = rb1;
        __syncthreads();
        if (it + 1 < 16) loadTile(it + 1);  // overlaps the MFMAs below

        const int kc = (kq ^ swz) * 8;      // swizzled chunk for this lane
        short8 a[4], b[4];
#pragma unroll
        for (int mt = 0; mt < 4; ++mt)
            a[mt] = *(const short8*)&As[buf][(wm + mt * 16 + l15) * 32 + kc];
#pragma unroll
        for (int nt = 0; nt < 4; ++nt)
            b[nt] = *(const short8*)&Bs[buf][(wn + nt * 16 + l15) * 32 + kc];
        // Swapped operands: D = C^T; lane l15 = C-row, regs = 4 consecutive cols
#pragma unroll
        for (int mt = 0; mt < 4; ++mt)
#pragma unroll
            for (int nt = 0; nt < 4; ++nt)
                acc[mt][nt] = __builtin_amdgcn_mfma_f32_16x16x32_bf16(
                    b[nt], a[mt], acc[mt][nt], 0, 0, 0);
    }

    // Epilogue (C^T layout): row = wm+mt*16+l15, cols = wn+nt*16+kq*4..+3
    u16* __restrict__ Cbase = (col0 < split) ? Cl : Cr;
    const int cadj = (col0 < split) ? col0 : (col0 - split);
#pragma unroll
    for (int mt = 0; mt < 4; ++mt) {
        int row = row0 + wm + mt * 16 + l15;
        if (row >= M) continue;
#pragma unroll
        for (int nt = 0; nt < 4; ++nt) {
            int c0 = cadj + wn + nt * 16 + kq * 4;
            uint2 o;
            o.x = (u32)f32_to_bf16(acc[mt][nt][0]) |
                  ((u32)f32_to_bf16(acc[mt][nt][1]) << 16);
            o.y = (u32)f32_to_bf16(acc[mt][nt][2]) |
                  ((u32)f32_to_bf16(acc[mt][nt][3]) << 16);
            *(uint2*)(Cbase + (size_t)row * split + c0) = o;
        }
    }
}

// h[node] = relu(mean(Yl[src]) + Yr[node] + bias), D=512 bf16.
// One wave per node; lane covers 8 cols (uint4).
__global__ __launch_bounds__(256) void gather_add_relu512(
    const u16* __restrict__ Yl, const u16* __restrict__ Yr,
    const float* __restrict__ bias,
    const int* __restrict__ row_start, const int* __restrict__ csr_src,
    u16* __restrict__ h, int M) {
    int node = (blockIdx.x * 256 + threadIdx.x) >> 6;
    int lane = threadIdx.x & 63;
    if (node >= M) return;
    int beg = row_start[node], end = row_start[node + 1];
    float a[8] = {0.f, 0.f, 0.f, 0.f, 0.f, 0.f, 0.f, 0.f};
    for (int c = beg; c < end; c += 64) {
        int nb = min(64, end - c);
        int eid = (lane < nb) ? csr_src[c + lane] : 0;
        for (int i = 0; i < nb; ++i) {
            int s = __shfl(eid, i);
            uint4 v = ((const uint4*)(Yl + (size_t)s * 512))[lane];
            a[0] += bf16_to_f32(v.x & 0xffffu); a[1] += bf16_to_f32(v.x >> 16);
            a[2] += bf16_to_f32(v.y & 0xffffu); a[3] += bf16_to_f32(v.y >> 16);
            a[4] += bf16_to_f32(v.z & 0xffffu); a[5] += bf16_to_f32(v.z >> 16);
            a[6] += bf16_to_f32(v.w & 0xffffu); a[7] += bf16_to_f32(v.w >> 16);
        }
    }
    float inv = 1.0f / fmaxf((float)(end - beg), 1.0f);
    uint4 yr = ((const uint4*)(Yr + (size_t)node * 512))[lane];
    float4 b0 = ((const float4*)bias)[lane * 2];
    float4 b1 = ((const float4*)bias)[lane * 2 + 1];
    float v0 = fmaxf(a[0] * inv + bf16_to_f32(yr.x & 0xffffu) + b0.x, 0.f);
    float v1 = fmaxf(a[1] * inv + bf16_to_f32(yr.x >> 16)     + b0.y, 0.f);
    float v2 = fmaxf(a[2] * inv + bf16_to_f32(yr.y & 0xffffu) + b0.z, 0.f);
    float v3 = fmaxf(a[3] * inv + bf16_to_f32(yr.y >> 16)     + b0.w, 0.f);
    float v4 = fmaxf(a[4] * inv + bf16_to_f32(yr.z & 0xffffu) + b1.x, 0.f);
    float v5 = fmaxf(a[5] * inv + bf16_to_f32(yr.z >> 16)     + b1.y, 0.f);
    float v6 = fmaxf(a[6] * inv + bf16_to_f32(yr.w & 0xffffu) + b1.z, 0.f);
    float v7 = fmaxf(a[7] * inv + bf16_to_f32(yr.w >> 16)     + b1.w, 0.f);
    uint4 o;
    o.x = (u32)f32_to_bf16(v0) | ((u32)f32_to_bf16(v1) << 16);
    o.y = (u32)f32_to_bf16(v2) | ((u32)f32_to_bf16(v3) << 16);
    o.z = (u32)f32_to_bf16(v4) | ((u32)f32_to_bf16(v5) << 16);
    o.w = (u32)f32_to_bf16(v6) | ((u32)f32_to_bf16(v7) << 16);
    ((uint4*)(h + (size_t)node * 512))[lane] = o;
}

// out[node] = log_softmax(mean(Yl[src]) + Yr[node] + bias), D=128, f32 out.
// 16 lanes per node (4 nodes/wave); lane covers 8 cols.
__global__ __launch_bounds__(256) void gather_add_lsm128(
    const u16* __restrict__ Yl, const u16* __restrict__ Yr,
    const float* __restrict__ bias,
    const int* __restrict__ row_start, const int* __restrict__ csr_src,
    float* __restrict__ out, int M) {
    int node = blockIdx.x * 16 + (threadIdx.x >> 4);
    int lane = threadIdx.x & 63;
    int li = lane & 15;
    int gbase = lane & 48;      // group base lane within wave
    if (node >= M) return;
    int beg = row_start[node], end = row_start[node + 1];
    float a[8] = {0.f, 0.f, 0.f, 0.f, 0.f, 0.f, 0.f, 0.f};
    for (int c = beg; c < end; c += 16) {
        int nb = min(16, end - c);
        int eid = (li < nb) ? csr_src[c + li] : 0;
        for (int i = 0; i < nb; ++i) {
            int s = __shfl(eid, gbase + i);
            uint4 v = ((const uint4*)(Yl + (size_t)s * 128))[li];
            a[0] += bf16_to_f32(v.x & 0xffffu); a[1] += bf16_to_f32(v.x >> 16);
            a[2] += bf16_to_f32(v.y & 0xffffu); a[3] += bf16_to_f32(v.y >> 16);
            a[4] += bf16_to_f32(v.z & 0xffffu); a[5] += bf16_to_f32(v.z >> 16);
            a[6] += bf16_to_f32(v.w & 0xffffu); a[7] += bf16_to_f32(v.w >> 16);
        }
    }
    float inv = 1.0f / fmaxf((float)(end - beg), 1.0f);
    uint4 yr = ((const uint4*)(Yr + (size_t)node * 128))[li];
    float4 b0 = ((const float4*)bias)[li * 2];
    float4 b1 = ((const float4*)bias)[li * 2 + 1];
    float v[8];
    v[0] = a[0] * inv + bf16_to_f32(yr.x & 0xffffu) + b0.x;
    v[1] = a[1] * inv + bf16_to_f32(yr.x >> 16)     + b0.y;
    v[2] = a[2] * inv + bf16_to_f32(yr.y & 0xffffu) + b0.z;
    v[3] = a[3] * inv + bf16_to_f32(yr.y >> 16)     + b0.w;
    v[4] = a[4] * inv + bf16_to_f32(yr.z & 0xffffu) + b1.x;
    v[5] = a[5] * inv + bf16_to_f32(yr.z >> 16)     + b1.y;
    v[6] = a[6] * inv + bf16_to_f32(yr.w & 0xffffu) + b1.z;
    v[7] = a[7] * inv + bf16_to_f32(yr.w >> 16)     + b1.w;
    float m = v[0];
#pragma unroll
    for (int j = 1; j < 8; ++j) m = fmaxf(m, v[j]);
#pragma unroll
    for (int off = 1; off < 16; off <<= 1) m = fmaxf(m, __shfl_xor(m, off));
    float s = 0.f;
#pragma unroll
    for (int j = 0; j < 8; ++j) s += expf(v[j] - m);
#pragma unroll
    for (int off = 1; off < 16; off <<= 1) s += __shfl_xor(s, off);
    float ls = m + logf(s);
    float* p = out + (size_t)node * 128 + li * 8;
    *(float4*)p       = make_float4(v[0] - ls, v[1] - ls, v[2] - ls, v[3] - ls);
    *(float4*)(p + 4) = make_float4(v[4] - ls, v[5] - ls, v[6] - ls, v[7] - ls);
}

extern "C" void kernel_launch(void* const* d_in, const int* in_sizes, int n_in,
                              void* d_out, int out_size, void* d_ws, size_t ws_size,
                              hipStream_t stream) {
    const float* x    = (const float*)d_in[0];
    const int*   ei   = (const int*)d_in[1];
    const float* W1_l = (const float*)d_in[2];
    const float* b1   = (const float*)d_in[3];
    const float* W1_r = (const float*)d_in[4];
    const float* W2_l = (const float*)d_in[5];
    const float* b2   = (const float*)d_in[6];
    const float* W2_r = (const float*)d_in[7];
    const float* W3_l = (const float*)d_in[8];
    const float* b3   = (const float*)d_in[9];
    const float* W3_r = (const float*)d_in[10];
    float* out = (float*)d_out;

    const int* src = ei;
    const int* dst = ei + N_EDGES;

    // Workspace layout (bytes from base):
    char* base = (char*)d_ws;
    int* row_start = (int*)(base);                    // 50052 ints
    int* cursor    = (int*)(base + 200208);           // 50052 ints
    int* bsums     = (int*)(base + 400416);           // 512 ints
    int* csr_src   = (int*)(base + 402464);           // 400000 ints -> end 2002464
    u16* xb  = (u16*)(base + 2002464);                // [M][512] bf16
    u16* h1b = (u16*)(base + 53202464);               // [M][512]
    u16* h2b = (u16*)(base + 104402464);              // [M][512]
    u16* Yl  = (u16*)(base + 155602464);              // [M][512] (layer3: [M][128])
    u16* Yr  = (u16*)(base + 206802464);              // [M][512] (layer3: [M][128])
    u16* w1T = (u16*)(base + 258002464);              // [1024][512]
    u16* w2T = (u16*)(base + 259051040);              // [1024][512]
    u16* w3T = (u16*)(base + 260099616);              // [256][512] -> end 260361760

    const int E = N_EDGES, M = N_NODES;
    const int nblk = (M + 255) / 256;

    // ---- CSR build ----
    zero4_kernel<<<(25154 + 255) / 256, 256, 0, stream>>>((float4*)d_ws, 25154);
    hist_kernel<<<(E + 255) / 256, 256, 0, stream>>>(dst, row_start, E);
    scan_reduce<<<nblk, 256, 0, stream>>>(row_start, bsums, M);
    scan_sums<<<1, 256, 0, stream>>>(bsums, nblk);
    scan_final<<<nblk, 256, 0, stream>>>(row_start, bsums, M);
    fill_kernel<<<(E + 255) / 256, 256, 0, stream>>>(src, dst, row_start, cursor,
                                                     csr_src, E);

    // ---- conversions: x -> bf16; weights -> WT [N][K] bf16, l/r concat ----
    convert_bf16<<<(3200000 + 255) / 256, 256, 0, stream>>>(x, xb, 3200000);
    transpose_w<<<dim3(16, 16), 256, 0, stream>>>(W1_l, w1T, 512, 512);
    transpose_w<<<dim3(16, 16), 256, 0, stream>>>(W1_r, w1T + 512 * 512, 512, 512);
    transpose_w<<<dim3(16, 16), 256, 0, stream>>>(W2_l, w2T, 512, 512);
    transpose_w<<<dim3(16, 16), 256, 0, stream>>>(W2_r, w2T + 512 * 512, 512, 512);
    transpose_w<<<dim3(4, 16), 256, 0, stream>>>(W3_l, w3T, 512, 128);
    transpose_w<<<dim3(4, 16), 256, 0, stream>>>(W3_r, w3T + 128 * 512, 512, 128);

    const int nStrips = (M + 127) / 128;                 // 391
    const int grid8 = ((nStrips + 7) / 8) * 64;          // 3136 (nCols=8)
    const int grid2 = ((nStrips + 7) / 8) * 16;          // 784  (nCols=2)
    const int gblocks = (M * 64 + 255) / 256;            // wave/node
    const int g16blocks = (M + 15) / 16;                 // 16 lanes/node

    // ---- layer 1: Y = x@[W1_l|W1_r]; h1 = relu(gather(Yl)+Yr+b1) ----
    gemm_bf16<<<grid8, 256, 0, stream>>>(xb, w1T, Yl, Yr, M, 512, nStrips, 8);
    gather_add_relu512<<<gblocks, 256, 0, stream>>>(Yl, Yr, b1, row_start,
                                                    csr_src, h1b, M);
    // ---- layer 2 ----
    gemm_bf16<<<grid8, 256, 0, stream>>>(h1b, w2T, Yl, Yr, M, 512, nStrips, 8);
    gather_add_relu512<<<gblocks, 256, 0, stream>>>(Yl, Yr, b2, row_start,
                                                    csr_src, h2b, M);
    // ---- layer 3: Y3 = h2@[W3_l|W3_r]; out = lsm(gather(Y3l)+Y3r+b3) ----
    gemm_bf16<<<grid2, 256, 0, stream>>>(h2b, w3T, Yl, Yr, M, 128, nStrips, 2);
    gather_add_lsm128<<<g16blocks, 256, 0, stream>>>(Yl, Yr, b3, row_start,
                                                     csr_src, out, M);
}